// Round 7
// baseline (4218.881 us; speedup 1.0000x reference)
//
#include <hip/hip_runtime.h>

#define ZB 202
#define ZBP 208            // imgT row stride (floats): [0,1,2]=zeros(bands -3..-1), 3+z=band z
#define YX 65536
#define NTOT ((size_t)ZB * YX)

#define SS 128             // steps per superstep (LDS: 2 x 128 x 256B = 64 KB)
#define NSS (YX / SS)      // 512 supersteps
#define PAD 4              // front slack so lanes 0-2's (lane-3) reads stay in-bounds

__device__ __forceinline__ constexpr float kMU() { return 0.0009765625f; }  // 2^-10
#define MINV (-32768.0f)
#define MAXV (32767.0f)

typedef float v2f __attribute__((ext_vector_type(2)));

// ---------------------------------------------------------------------------
// Phase A: transpose img[z][t] -> imgT[t*ZBP + 3 + z], with imgT[t*ZBP+{0,1,2}]=0
// (zero-padded bands -3..-1) and tail offsets 205..207 zeroed. (unchanged,
// verified round 3)
// ---------------------------------------------------------------------------
__global__ __launch_bounds__(256) void tr_kernel(const float* __restrict__ img,
                                                 float* __restrict__ imgT) {
    __shared__ float lds[64 * 65];
    const int t0 = blockIdx.x * 64;
    const int zi = blockIdx.y;           // 0..3
    const int zw0 = zi * 64 - 3;         // window band base
    const int tid = threadIdx.x;
    const int c = tid & 63;
    const int r0 = tid >> 6;

    for (int k = 0; k < 16; ++k) {
        int rr = r0 * 16 + k;
        int z = zw0 + rr;
        float v = 0.0f;
        if (z >= 0 && z < ZB) v = img[(size_t)z * YX + t0 + c];  // coalesced along t
        lds[rr * 65 + c] = v;
    }
    __syncthreads();

    const int l = tid & 63;
    const int off = zi * 64 + l;
    if (off < ZBP) {
        for (int k = 0; k < 16; ++k) {
            int tr = r0 * 16 + k;
            imgT[(size_t)(t0 + tr) * ZBP + off] = lds[l * 65 + tr];  // coalesced along z
        }
    }
}

// ---------------------------------------------------------------------------
// Phase B: sequential sign-LMS scan — producer/consumer block, 8 waves.
//
// Round-6 post-mortem: the ~145 cyc per global_load_lds wall is PER-CU, not
// per-wave (16,300 cyc/superstep = 128 DMAs x ~128 cyc; 7 producer waves
// gained nothing per-DMA).  Fix: producers stage via the ordinary VMEM path
// (global_load_dwordx4 -> 5x float4 regs -> ds_write_b128).  Each wave's
// buffer is only 20 VGPRs (too small for the compiler to sink, unlike the
// 64-128-VGPR buffers of rounds 0/4); 7 waves give TLP; producer time
// ~1.2k cyc/superstep, hidden under the consumer's ~5k cyc.
//   - lane -> (row k*4+lane>>4, col (lane&15)*4): 16 lanes cover one 256B row,
//     one dwordx4 load covers 4 rows.
//   - out-of-range rows: loads run unclamped (land in the dead gap between
//     imgT end (~54.6MB) and dT start (211.8MB) -- in-bounds of d_out);
//     writes steer branchlessly to a dummy LDS slot via address select.
// LDS bits consumed are identical to rounds 3/5/6.
//
// Consumer unchanged (round-6 verified): inline-asm ds_read2_b32 batches per
// 16-step sub-tile, lgkmcnt(0)+sched_barrier drain, ra/rb ping-pong.
// Data path bit-exact: {n2,n1,n0,s} = LDS dwords {lane-3..lane}; d = 3-mul +
// left-to-right 2-add; sign(s-clip(d))==sign(s-d) since |s|<32767; w' =
// fma(+-MU,n,w); stores UNCLIPPED d (finalize clamps).  Lanes 0-2 feeders.
// ---------------------------------------------------------------------------
__global__ __launch_bounds__(512, 1) void scan_kernel(const float* __restrict__ imgT,
                                                      const float* __restrict__ w0g,
                                                      float* __restrict__ dT) {
    __shared__ float ldsf[PAD + 2 * SS * 64 + 64];  // +64: dummy write slot

    const int tid = threadIdx.x;
    const int lane = tid & 63;
    const int wv = tid >> 6;                  // 0 = consumer, 1..7 = producers
    const int b = blockIdx.x;                 // 0..3

    // consumer-only state (harmless on producers)
    const int band = 61 * b + lane - 3;
    const bool do_store = (lane >= 3) && (band < ZB);
    const int wband = band < 0 ? 0 : (band > ZB - 1 ? ZB - 1 : band);
    float w0 = w0g[wband * 3 + 0];
    float w1 = w0g[wband * 3 + 1];
    float w2 = w0g[wband * 3 + 2];
    float* outp = dT + wband;                 // dT[t][z] layout, stride ZB

    // producer lane mapping: 16 lanes per row, 4 rows per dwordx4 load
    const int sub = lane >> 4;                // row subgroup 0..3
    const int col = (lane & 15) * 4;          // float column within row
    float* const dummy = ldsf + PAD + 2 * SS * 64;

    // producer: stage superstep st into buffer st&1 (rows r = wv-1 + 7k)
    auto stage = [&](int st) {
        float* lbase = ldsf + PAD + (st & 1) * (SS * 64);
        const float* gbase = imgT + 61 * b + (size_t)st * (SS * ZBP) + col;
        float4 v[5];
        int rr[5];
#pragma unroll
        for (int g = 0; g < 5; ++g) {
            rr[g] = (wv - 1) + 7 * (4 * g + sub);
            v[g] = *(const float4*)(gbase + (size_t)rr[g] * ZBP);  // unclamped: dead-gap junk ok
        }
#pragma unroll
        for (int g = 0; g < 5; ++g) {
            float* lp = (rr[g] < SS) ? (lbase + rr[g] * 64 + col) : (dummy + col);
            *(float4*)lp = v[g];              // ds_write_b128, address-selected
        }
    };

    float4 ra[16], rb[16];

    // batch-ISSUE one 16-step sub-tile: 16x asm {ds_read2_b32 x2} -> 64 dwords.
    // Volatile asm defs are unsinkable; data valid only after KWAIT().
#define RTISSUE(dst, st_)                                                      \
    {                                                                          \
        uint32_t a0 = (uint32_t)(size_t)(__attribute__((address_space(3)))     \
            float*)(ldsf + (PAD + (ss & 1) * (SS * 64) + (st_) * (16 * 64)     \
                            + lane - 3));                                      \
        _Pragma("unroll") for (int k = 0; k < 16; ++k) {                       \
            v2f p01, p23;                                                      \
            uint32_t a = a0 + (uint32_t)(k * 256);                             \
            asm volatile("ds_read2_b32 %0, %2 offset0:0 offset1:1\n\t"         \
                         "ds_read2_b32 %1, %2 offset0:2 offset1:3"             \
                         : "=v"(p01), "=v"(p23)                                \
                         : "v"(a));                                            \
            dst[k].x = p01.x; dst[k].y = p01.y;                                \
            dst[k].z = p23.x; dst[k].w = p23.y;                                \
        }                                                                      \
    }

#define KWAIT()                                                                \
    {                                                                          \
        asm volatile("s_waitcnt lgkmcnt(0)" ::: "memory");                     \
        __builtin_amdgcn_sched_barrier(0);                                     \
    }

#define CP(buf, st_)                                                           \
    {                                                                          \
        float* op = outp + ((size_t)ss * SS + (st_) * 16) * ZB;                \
        _Pragma("unroll") for (int i = 0; i < 16; ++i) {                       \
            const float4 v = buf[i];                                           \
            float d = __fadd_rn(                                               \
                __fadd_rn(__fmul_rn(w0, v.z), __fmul_rn(w1, v.y)),             \
                __fmul_rn(w2, v.x));                                           \
            float sg = (v.w > d) ? kMU() : ((v.w < d) ? -kMU() : 0.0f);        \
            w0 = __builtin_fmaf(sg, v.z, w0);                                  \
            w1 = __builtin_fmaf(sg, v.y, w1);                                  \
            w2 = __builtin_fmaf(sg, v.x, w2);                                  \
            if (do_store) op[(size_t)i * ZB] = d;                              \
        }                                                                      \
    }

    if (wv != 0) stage(0);
    __syncthreads();

    for (int ss = 0; ss < NSS; ++ss) {
        if (wv != 0) {
            if (ss + 1 < NSS) stage(ss + 1);
        } else {
            // 8 sub-tiles of 16 steps; batch-issue one sub-tile ahead
            RTISSUE(ra, 0); KWAIT();
            RTISSUE(rb, 1); CP(ra, 0); KWAIT();
            RTISSUE(ra, 2); CP(rb, 1); KWAIT();
            RTISSUE(rb, 3); CP(ra, 2); KWAIT();
            RTISSUE(ra, 4); CP(rb, 3); KWAIT();
            RTISSUE(rb, 5); CP(ra, 4); KWAIT();
            RTISSUE(ra, 6); CP(rb, 5); KWAIT();
            RTISSUE(rb, 7); CP(ra, 6); KWAIT();
            CP(rb, 7);
        }
        __syncthreads();  // producers' ds_writes visible before consumer reuses buffer
    }

#undef RTISSUE
#undef KWAIT
#undef CP
}

// ---------------------------------------------------------------------------
// Phase C: elementwise outputs from dT + image. (unchanged, verified)
// ---------------------------------------------------------------------------
__global__ __launch_bounds__(256) void finalize_kernel(const float* __restrict__ img,
                                                       const float* __restrict__ dT,
                                                       float* __restrict__ out) {
    __shared__ float lds[64 * ZB];  // 51.7 KB
    const int t0 = blockIdx.x * 64;
    const float* src = dT + (size_t)t0 * ZB;
    for (int i = threadIdx.x; i < 64 * ZB; i += 256) lds[i] = src[i];
    __syncthreads();

    for (int k = 0; k < 51; ++k) {
        int e = k * 256 + threadIdx.x;
        if (e < 64 * ZB) {
            int zz = e >> 6;
            int tl = e & 63;
            float dv = lds[tl * ZB + zz];            // stride 202 -> 2-way bank alias (free)
            float pred = fminf(fmaxf(dv, MINV), MAXV);
            size_t o = (size_t)zz * YX + t0 + tl;
            float s = img[o];
            float res = __fsub_rn(s, pred);
            int q = (int)rintf(res);                  // round-half-even == jnp.round
            int m = (q >= 0) ? (2 * q) : (-2 * q - 1);
            out[o] = pred;                            // predictions
            out[NTOT + o] = res;                      // residuals
            out[2 * NTOT + o] = res;                  // quantized_residuals
            out[3 * NTOT + o] = (float)m;             // mapped_indices
            out[5 * NTOT + o] = __fadd_rn(pred, res); // reconstructed
        }
    }
}

// ---------------------------------------------------------------------------
// Phase D: sample_representatives = image. (unchanged)
// ---------------------------------------------------------------------------
__global__ __launch_bounds__(256) void repr_kernel(const float4* __restrict__ img4,
                                                   float4* __restrict__ out4) {
    size_t n4 = NTOT / 4;
    for (size_t i = (size_t)blockIdx.x * blockDim.x + threadIdx.x; i < n4;
         i += (size_t)gridDim.x * blockDim.x)
        out4[i] = img4[i];
}

extern "C" void kernel_launch(void* const* d_in, const int* in_sizes, int n_in,
                              void* d_out, int out_size, void* d_ws, size_t ws_size,
                              hipStream_t stream) {
    const float* img = (const float*)d_in[0];
    const float* w0g = (const float*)d_in[1];
    float* out = (float*)d_out;

    // Scratch carved out of d_out (dead before the final writers touch it):
    //   imgT = out[0 .. YX*ZBP+64) floats (54.5 MB; producer over-reads of up
    //          to ~12 rows past a superstep land in the dead gap before dT at
    //          4N floats = 211.8 MB -- always in-bounds of d_out)
    //   dT   = out[4N .. 5N) floats (later overwritten by repr_kernel)
    float* imgT = out;
    float* dT = out + 4 * NTOT;

    tr_kernel<<<dim3(YX / 64, 4), 256, 0, stream>>>(img, imgT);
    scan_kernel<<<4, 512, 0, stream>>>(imgT, w0g, dT);
    finalize_kernel<<<YX / 64, 256, 0, stream>>>(img, dT, out);
    repr_kernel<<<4096, 256, 0, stream>>>((const float4*)img, (float4*)(out + 4 * NTOT));
}